// Round 3
// baseline (545.611 us; speedup 1.0000x reference)
//
#include <hip/hip_runtime.h>
#include <cstdint>
#include <cstddef>

#define B_TOK 8192
#define HDIM  2048
#define CDIM  256
#define KHV   4096   // 2*H
#define N3H   6144   // 3*H
#define DT_C  0.1f

typedef __bf16 bf16x8 __attribute__((ext_vector_type(8)));
typedef float  f32x4  __attribute__((ext_vector_type(4)));

typedef __attribute__((address_space(1))) void as1_void;
typedef __attribute__((address_space(3))) void as3_void;

// async global->LDS, 16B per lane; LDS dst = wave-uniform base + lane*16
__device__ __forceinline__ void g2l16(const void* g, void* l) {
    __builtin_amdgcn_global_load_lds((as1_void*)(void*)(uintptr_t)(g),
                                     (as3_void*)l, 16, 0, 0);
}

__device__ __forceinline__ unsigned short f2bf(float f) {
    unsigned int u = __float_as_uint(f);
    u += 0x7fffu + ((u >> 16) & 1u);   // RNE
    return (unsigned short)(u >> 16);
}

__device__ __forceinline__ float bf2f(unsigned short s) {
    return __uint_as_float((unsigned int)s << 16);
}

// fast sigmoid: v_exp + v_rcp (no full-precision divide)
__device__ __forceinline__ float fsigmoid(float x) {
    return __builtin_amdgcn_rcpf(1.f + __expf(-x));
}
// fast softplus: max(x,0) + ln2*log2(1+exp(-|x|)), all native v_exp/v_log
__device__ __forceinline__ float fsoftplus(float x) {
    float t = __expf(-fabsf(x));
    return fmaxf(x, 0.f) + 0.69314718056f * __log2f(1.f + t);
}

// ---------------- K0: fp32 -> bf16 conversion (hv concat + weights) -------
__global__ void k_convert(const float* __restrict__ hp, const float* __restrict__ vp,
                          const float* __restrict__ Win, const float* __restrict__ Wout,
                          const float* __restrict__ Wmu,
                          ushort4* __restrict__ hv_b, ushort4* __restrict__ Wmu_b,
                          ushort4* __restrict__ Wout_b, ushort4* __restrict__ Win_b)
{
    const int HV_V   = B_TOK * KHV / 4;    // 8388608 vec4
    const int WMU_V  = HDIM * HDIM / 4;    // 1048576
    const int WOUT_V = N3H * CDIM / 4;     // 393216
    const int WIN_V  = CDIM * KHV / 4;     // 262144
    const int TOT    = HV_V + WMU_V + WOUT_V + WIN_V;
    for (int i = blockIdx.x * blockDim.x + threadIdx.x; i < TOT;
         i += gridDim.x * blockDim.x) {
        float4 x;
        ushort4* dst;
        if (i < HV_V) {
            int b  = i >> 10;          // row (4096/4 = 1024 vec4 per row)
            int c4 = i & 1023;
            x = (c4 < 512) ? ((const float4*)hp)[b * 512 + c4]
                           : ((const float4*)vp)[b * 512 + (c4 - 512)];
            dst = hv_b + i;
        } else if (i < HV_V + WMU_V) {
            int j = i - HV_V;
            x = ((const float4*)Wmu)[j];
            dst = Wmu_b + j;
        } else if (i < HV_V + WMU_V + WOUT_V) {
            int j = i - (HV_V + WMU_V);
            x = ((const float4*)Wout)[j];
            dst = Wout_b + j;
        } else {
            int j = i - (HV_V + WMU_V + WOUT_V);
            x = ((const float4*)Win)[j];
            dst = Win_b + j;
        }
        ushort4 o;
        o.x = f2bf(x.x); o.y = f2bf(x.y); o.z = f2bf(x.z); o.w = f2bf(x.w);
        *dst = o;
    }
}

// ---------------- K1a: ctrl partials (split-K x4), raw fp32 --------------
// A = hv_b [8192 x 4096], Bw = Win_b [256 x 4096] (BT layout)
// grid (bn=4, bm=128, ks=4); BM=BN=64, BK=32; per-block K-range 1024
__global__ void k_gemm1(const unsigned short* __restrict__ A,
                        const unsigned short* __restrict__ Bw,
                        float* __restrict__ ctrl_p)   // [4][B_TOK*CDIM]
{
    __shared__ unsigned short sA[64 * 32];
    __shared__ unsigned short sB[64 * 32];
    const int tid  = threadIdx.x;
    const int wid  = tid >> 6;
    const int lane = tid & 63;
    const int quad = lane >> 4;
    const int l15  = lane & 15;
    const int wm   = wid >> 1, wn = wid & 1;
    const int bn   = blockIdx.x * 64;
    const int bm   = blockIdx.y * 64;
    const int ks   = blockIdx.z;
    const int k0   = ks * 1024;
    const int srow = lane >> 2;        // 0..15
    const int sk   = (lane & 3) * 8;   // k element offset 0/8/16/24

    f32x4 acc[2][2];
#pragma unroll
    for (int a = 0; a < 2; ++a)
#pragma unroll
        for (int b = 0; b < 2; ++b) acc[a][b] = (f32x4){0.f, 0.f, 0.f, 0.f};

    const unsigned short* Ag = A  + (size_t)(bm + wid * 16 + srow) * KHV + sk;
    const unsigned short* Bg = Bw + (size_t)(bn + wid * 16 + srow) * KHV + sk;
    unsigned short* lA = &sA[(wid * 16) * 32];
    unsigned short* lB = &sB[(wid * 16) * 32];

    for (int kt = k0; kt < k0 + 1024; kt += 32) {
        g2l16(Ag + kt, lA);
        g2l16(Bg + kt, lB);
        __syncthreads();
        bf16x8 aF[2], bF[2];
#pragma unroll
        for (int t = 0; t < 2; ++t)
            aF[t] = *(const bf16x8*)&sA[(wm * 32 + t * 16 + l15) * 32 + quad * 8];
#pragma unroll
        for (int t = 0; t < 2; ++t)
            bF[t] = *(const bf16x8*)&sB[(wn * 32 + t * 16 + l15) * 32 + quad * 8];
#pragma unroll
        for (int tm = 0; tm < 2; ++tm)
#pragma unroll
            for (int tn = 0; tn < 2; ++tn)
                acc[tm][tn] = __builtin_amdgcn_mfma_f32_16x16x32_bf16(
                    aF[tm], bF[tn], acc[tm][tn], 0, 0, 0);
        __syncthreads();
    }

    float* outp = ctrl_p + (size_t)ks * B_TOK * CDIM;
#pragma unroll
    for (int tm = 0; tm < 2; ++tm)
#pragma unroll
        for (int tn = 0; tn < 2; ++tn) {
            const int n = bn + wn * 32 + tn * 16 + l15;
#pragma unroll
            for (int r = 0; r < 4; ++r) {
                const int m = bm + wm * 32 + tm * 16 + quad * 4 + r;
                outp[(size_t)m * CDIM + n] = acc[tm][tn][r];
            }
        }
}

// ---------------- K1b: reduce 4 partials + bias + silu -> bf16 ctrl ------
__global__ void k_red(const float* __restrict__ ctrl_p,
                      const float* __restrict__ b_in,
                      ushort4* __restrict__ ctrl)
{
    const int TOT = B_TOK * CDIM / 4;   // 524288 float4
    const int P   = B_TOK * CDIM / 4;   // stride between partials in float4
    int i = blockIdx.x * blockDim.x + threadIdx.x;
    if (i >= TOT) return;
    const float4* p = (const float4*)ctrl_p;
    float4 s0 = p[i];
    float4 s1 = p[P + i];
    float4 s2 = p[2 * P + i];
    float4 s3 = p[3 * P + i];
    const int n4 = i & 63;              // 64 float4 per row of 256
    float4 bb = ((const float4*)b_in)[n4];
    float x0 = s0.x + s1.x + s2.x + s3.x + bb.x;
    float x1 = s0.y + s1.y + s2.y + s3.y + bb.y;
    float x2 = s0.z + s1.z + s2.z + s3.z + bb.z;
    float x3 = s0.w + s1.w + s2.w + s3.w + bb.w;
    ushort4 o;
    o.x = f2bf(x0 * fsigmoid(x0));
    o.y = f2bf(x1 * fsigmoid(x1));
    o.z = f2bf(x2 * fsigmoid(x2));
    o.w = f2bf(x3 * fsigmoid(x3));
    ctrl[i] = o;
}

// ---------------- K2: mu_ctx = mu + h @ Wmu^T (fp32 out to d_out+2BH) ----
// A = hv_b cols 0..2047 (lda=4096), Bw = Wmu_b [2048 x 2048]
// BM=BN=128, BK=32; 4 waves (2x2), wave tile 64x64 (4x4 MFMA)
// no launch_bounds: m97 parity (164 VGPR -> ~3 blocks/CU)
__global__ void k_gemm3(const unsigned short* __restrict__ A,
                        const unsigned short* __restrict__ Bw,
                        const float* __restrict__ mu,
                        float* __restrict__ outmu)
{
    __shared__ unsigned short sA[128 * 32];
    __shared__ unsigned short sB[128 * 32];
    const int tid  = threadIdx.x;
    const int wid  = tid >> 6;
    const int lane = tid & 63;
    const int quad = lane >> 4;
    const int l15  = lane & 15;
    const int wm   = wid >> 1, wn = wid & 1;
    const int bm   = blockIdx.x * 128;
    const int bn   = blockIdx.y * 128;
    const int srow = lane >> 2;
    const int sk   = (lane & 3) * 8;

    f32x4 acc[4][4];
#pragma unroll
    for (int a = 0; a < 4; ++a)
#pragma unroll
        for (int b = 0; b < 4; ++b) acc[a][b] = (f32x4){0.f, 0.f, 0.f, 0.f};

    const unsigned short* Ag0 = A  + (size_t)(bm + wid * 16 + srow) * KHV + sk;
    const unsigned short* Ag1 = A  + (size_t)(bm + (wid + 4) * 16 + srow) * KHV + sk;
    const unsigned short* Bg0 = Bw + (size_t)(bn + wid * 16 + srow) * HDIM + sk;
    const unsigned short* Bg1 = Bw + (size_t)(bn + (wid + 4) * 16 + srow) * HDIM + sk;
    unsigned short* lA0 = &sA[(wid * 16) * 32];
    unsigned short* lA1 = &sA[((wid + 4) * 16) * 32];
    unsigned short* lB0 = &sB[(wid * 16) * 32];
    unsigned short* lB1 = &sB[((wid + 4) * 16) * 32];

    for (int kt = 0; kt < HDIM; kt += 32) {
        g2l16(Ag0 + kt, lA0);
        g2l16(Ag1 + kt, lA1);
        g2l16(Bg0 + kt, lB0);
        g2l16(Bg1 + kt, lB1);
        __syncthreads();
        bf16x8 aF[4], bF[4];
#pragma unroll
        for (int t = 0; t < 4; ++t)
            aF[t] = *(const bf16x8*)&sA[(wm * 64 + t * 16 + l15) * 32 + quad * 8];
#pragma unroll
        for (int t = 0; t < 4; ++t)
            bF[t] = *(const bf16x8*)&sB[(wn * 64 + t * 16 + l15) * 32 + quad * 8];
#pragma unroll
        for (int tm = 0; tm < 4; ++tm)
#pragma unroll
            for (int tn = 0; tn < 4; ++tn)
                acc[tm][tn] = __builtin_amdgcn_mfma_f32_16x16x32_bf16(
                    aF[tm], bF[tn], acc[tm][tn], 0, 0, 0);
        __syncthreads();
    }

#pragma unroll
    for (int tm = 0; tm < 4; ++tm)
#pragma unroll
        for (int tn = 0; tn < 4; ++tn) {
            const int n = bn + wn * 64 + tn * 16 + l15;
            const float mub = mu[n];
#pragma unroll
            for (int r = 0; r < 4; ++r) {
                const int m = bm + wm * 64 + tm * 16 + quad * 4 + r;
                outmu[(size_t)m * HDIM + n] = acc[tm][tn][r] + mub;
            }
        }
}

// ---------------- K3: ctrl_out (3 planes) + full fused elementwise -------
// A = ctrl [8192 x 256] bf16, Bw = Wout_b [6144 x 256]
// BM=64, BN=64 per plane x 3 planes; 4 waves (2x2), wave tile 32x32/plane
// Epilogue uses native v_exp/v_log/v_rcp and bf16 h/v (from hv_b).
__global__ __launch_bounds__(256, 4)
void k_gemm2(const unsigned short* __restrict__ A,
             const unsigned short* __restrict__ Bw,
             const float* __restrict__ b_out,
             const unsigned short* __restrict__ hv,   // bf16 [B, 4096]: h | v
             const float* __restrict__ mu_ctx,
             float* __restrict__ outp)
{
    __shared__ unsigned short sA[64 * 32];
    __shared__ unsigned short sB[3][64 * 32];
    const int tid  = threadIdx.x;
    const int wid  = tid >> 6;
    const int lane = tid & 63;
    const int quad = lane >> 4;
    const int l15  = lane & 15;
    const int wm   = wid >> 1, wn = wid & 1;
    const int bm   = blockIdx.x * 64;
    const int bn   = blockIdx.y * 64;
    const int srow = lane >> 2;
    const int sk   = (lane & 3) * 8;

    f32x4 acc[3][2][2];
#pragma unroll
    for (int p = 0; p < 3; ++p)
#pragma unroll
        for (int a = 0; a < 2; ++a)
#pragma unroll
            for (int b = 0; b < 2; ++b) acc[p][a][b] = (f32x4){0.f, 0.f, 0.f, 0.f};

    const unsigned short* Ag  = A + (size_t)(bm + wid * 16 + srow) * CDIM + sk;
    const unsigned short* Bg0 = Bw + (size_t)(0 * HDIM + bn + wid * 16 + srow) * CDIM + sk;
    const unsigned short* Bg1 = Bw + (size_t)(1 * HDIM + bn + wid * 16 + srow) * CDIM + sk;
    const unsigned short* Bg2 = Bw + (size_t)(2 * HDIM + bn + wid * 16 + srow) * CDIM + sk;
    unsigned short* lA  = &sA[(wid * 16) * 32];
    unsigned short* lB0 = &sB[0][(wid * 16) * 32];
    unsigned short* lB1 = &sB[1][(wid * 16) * 32];
    unsigned short* lB2 = &sB[2][(wid * 16) * 32];

    for (int kt = 0; kt < CDIM; kt += 32) {
        g2l16(Ag  + kt, lA);
        g2l16(Bg0 + kt, lB0);
        g2l16(Bg1 + kt, lB1);
        g2l16(Bg2 + kt, lB2);
        __syncthreads();
        bf16x8 aF[2], bF[3][2];
#pragma unroll
        for (int t = 0; t < 2; ++t)
            aF[t] = *(const bf16x8*)&sA[(wm * 32 + t * 16 + l15) * 32 + quad * 8];
#pragma unroll
        for (int p = 0; p < 3; ++p)
#pragma unroll
            for (int t = 0; t < 2; ++t)
                bF[p][t] = *(const bf16x8*)&sB[p][(wn * 32 + t * 16 + l15) * 32 + quad * 8];
#pragma unroll
        for (int p = 0; p < 3; ++p)
#pragma unroll
            for (int tm = 0; tm < 2; ++tm)
#pragma unroll
                for (int tn = 0; tn < 2; ++tn)
                    acc[p][tm][tn] = __builtin_amdgcn_mfma_f32_16x16x32_bf16(
                        aF[tm], bF[p][tn], acc[p][tm][tn], 0, 0, 0);
        __syncthreads();
    }

#pragma unroll
    for (int tm = 0; tm < 2; ++tm)
#pragma unroll
        for (int tn = 0; tn < 2; ++tn) {
            const int i  = bn + wn * 32 + tn * 16 + l15;
            const float ba = b_out[i];
            const float bb = b_out[HDIM + i];
            const float bg = b_out[2 * HDIM + i];
#pragma unroll
            for (int r = 0; r < 4; ++r) {
                const int m = bm + wm * 32 + tm * 16 + quad * 4 + r;
                const size_t off = (size_t)m * HDIM + i;
                const float araw = acc[0][tm][tn][r] + ba;
                const float braw = acc[1][tm][tn][r] + bb;
                const float graw = acc[2][tm][tn][r] + bg;
                const float alpha = fsigmoid(araw);
                const float beta  = fminf(fsoftplus(braw), 2.f);
                const float gate  = fsigmoid(graw);
                const float hh = bf2f(hv[(size_t)m * KHV + i]);
                const float vv = bf2f(hv[(size_t)m * KHV + HDIM + i]);
                const float mm = mu_ctx[off];
                const float err = hh - mm;
                float vn = alpha * vv - beta * err;
                vn = fminf(fmaxf(vn, -10.f), 10.f);
                const float hn = hh + DT_C * gate * vn;
                outp[off] = hn;                              // h_next
                outp[(size_t)B_TOK * HDIM + off] = vn;       // v_next
            }
        }
}

extern "C" void kernel_launch(void* const* d_in, const int* in_sizes, int n_in,
                              void* d_out, int out_size, void* d_ws, size_t ws_size,
                              hipStream_t stream)
{
    const float* hp    = (const float*)d_in[0];
    const float* vp    = (const float*)d_in[1];
    const float* Win   = (const float*)d_in[2];
    const float* b_in  = (const float*)d_in[3];
    const float* Wout  = (const float*)d_in[4];
    const float* b_out = (const float*)d_in[5];
    const float* Wmu   = (const float*)d_in[6];
    const float* mu    = (const float*)d_in[7];
    float* outp = (float*)d_out;

    char* ws = (char*)d_ws;
    size_t off = 0;
    unsigned short* hv_b   = (unsigned short*)(ws + off); off += (size_t)B_TOK * KHV * 2;  // 64 MiB
    unsigned short* Wmu_b  = (unsigned short*)(ws + off); off += (size_t)HDIM * HDIM * 2;  //  8 MiB
    unsigned short* Wout_b = (unsigned short*)(ws + off); off += (size_t)N3H * CDIM * 2;   //  3 MiB
    unsigned short* Win_b  = (unsigned short*)(ws + off); off += (size_t)CDIM * KHV * 2;   //  2 MiB
    unsigned short* ctrl   = (unsigned short*)(ws + off); off += (size_t)B_TOK * CDIM * 2; //  4 MiB
    float*          ctrl_p = (float*)(ws + off);          off += (size_t)4 * B_TOK * CDIM * 4; // 32 MiB
    // total ws use ~113 MiB

    k_convert<<<dim3(4096), dim3(256), 0, stream>>>(
        hp, vp, Win, Wout, Wmu,
        (ushort4*)hv_b, (ushort4*)Wmu_b, (ushort4*)Wout_b, (ushort4*)Win_b);

    // split-K x4 ctrl partials; bn fastest so A-tile sharers are adjacent
    k_gemm1<<<dim3(4, 128, 4), dim3(256), 0, stream>>>(hv_b, Win_b, ctrl_p);
    k_red<<<dim3(2048), dim3(256), 0, stream>>>(ctrl_p, b_in, (ushort4*)ctrl);

    k_gemm3<<<dim3(64, 16), dim3(256), 0, stream>>>(
        hv_b, Wmu_b, mu, outp + (size_t)2 * B_TOK * HDIM);

    k_gemm2<<<dim3(128, 32), dim3(256), 0, stream>>>(
        ctrl, Wout_b, b_out, hv_b,
        outp + (size_t)2 * B_TOK * HDIM, outp);
}

// Round 4
// 510.429 us; speedup vs baseline: 1.0689x; 1.0689x over previous
//
#include <hip/hip_runtime.h>
#include <cstdint>
#include <cstddef>

#define B_TOK 8192
#define HDIM  2048
#define CDIM  256
#define KHV   4096   // 2*H
#define N3H   6144   // 3*H
#define DT_C  0.1f

typedef __bf16 bf16x8 __attribute__((ext_vector_type(8)));
typedef float  f32x4  __attribute__((ext_vector_type(4)));

typedef __attribute__((address_space(1))) void as1_void;
typedef __attribute__((address_space(3))) void as3_void;

// async global->LDS, 16B per lane; LDS dst = wave-uniform base + lane*16
__device__ __forceinline__ void g2l16(const void* g, void* l) {
    __builtin_amdgcn_global_load_lds((as1_void*)(void*)(uintptr_t)(g),
                                     (as3_void*)l, 16, 0, 0);
}

__device__ __forceinline__ unsigned short f2bf(float f) {
    unsigned int u = __float_as_uint(f);
    u += 0x7fffu + ((u >> 16) & 1u);   // RNE
    return (unsigned short)(u >> 16);
}

__device__ __forceinline__ float bf2f(unsigned short s) {
    return __uint_as_float((unsigned int)s << 16);
}

// fast sigmoid: v_exp + v_rcp (no full-precision divide)
__device__ __forceinline__ float fsigmoid(float x) {
    return __builtin_amdgcn_rcpf(1.f + __expf(-x));
}
// fast softplus: max(x,0) + ln2*log2(1+exp(-|x|)), all native v_exp/v_log
__device__ __forceinline__ float fsoftplus(float x) {
    float t = __expf(-fabsf(x));
    return fmaxf(x, 0.f) + 0.69314718056f * __log2f(1.f + t);
}

// ---------------- K0: fp32 -> bf16 conversion (hv concat + weights) -------
__global__ void k_convert(const float* __restrict__ hp, const float* __restrict__ vp,
                          const float* __restrict__ Win, const float* __restrict__ Wout,
                          const float* __restrict__ Wmu,
                          ushort4* __restrict__ hv_b, ushort4* __restrict__ Wmu_b,
                          ushort4* __restrict__ Wout_b, ushort4* __restrict__ Win_b)
{
    const int HV_V   = B_TOK * KHV / 4;    // 8388608 vec4
    const int WMU_V  = HDIM * HDIM / 4;    // 1048576
    const int WOUT_V = N3H * CDIM / 4;     // 393216
    const int WIN_V  = CDIM * KHV / 4;     // 262144
    const int TOT    = HV_V + WMU_V + WOUT_V + WIN_V;
    for (int i = blockIdx.x * blockDim.x + threadIdx.x; i < TOT;
         i += gridDim.x * blockDim.x) {
        float4 x;
        ushort4* dst;
        if (i < HV_V) {
            int b  = i >> 10;          // row (4096/4 = 1024 vec4 per row)
            int c4 = i & 1023;
            x = (c4 < 512) ? ((const float4*)hp)[b * 512 + c4]
                           : ((const float4*)vp)[b * 512 + (c4 - 512)];
            dst = hv_b + i;
        } else if (i < HV_V + WMU_V) {
            int j = i - HV_V;
            x = ((const float4*)Wmu)[j];
            dst = Wmu_b + j;
        } else if (i < HV_V + WMU_V + WOUT_V) {
            int j = i - (HV_V + WMU_V);
            x = ((const float4*)Wout)[j];
            dst = Wout_b + j;
        } else {
            int j = i - (HV_V + WMU_V + WOUT_V);
            x = ((const float4*)Win)[j];
            dst = Win_b + j;
        }
        ushort4 o;
        o.x = f2bf(x.x); o.y = f2bf(x.y); o.z = f2bf(x.z); o.w = f2bf(x.w);
        *dst = o;
    }
}

// ---------------- K_mid: fat kernel = gemm1 (blocks 0..511) + gemm3 ------
// gemm1: ctrl = silu(hv @ Win^T + b_in), BM=BN=64, 512 blocks
// gemm3: mu_ctx = mu + h @ Wmu^T, BM=BN=128, 1024 blocks (blocks 512..1535)
// Independent work items co-resident on each CU: gemm1 is staging/latency-
// heavy (K=4096, small tile), gemm3 is MFMA-dense -> m114-style overlap.
__global__ __launch_bounds__(256, 2)
void k_mid(const unsigned short* __restrict__ hvb,
           const unsigned short* __restrict__ Winb,
           const unsigned short* __restrict__ Wmub,
           const float* __restrict__ b_in,
           const float* __restrict__ mu,
           unsigned short* __restrict__ ctrl,
           float* __restrict__ outmu)
{
    __shared__ unsigned short sA[128 * 32];
    __shared__ unsigned short sB[128 * 32];
    const int tid  = threadIdx.x;
    const int wid  = tid >> 6;
    const int lane = tid & 63;
    const int quad = lane >> 4;
    const int l15  = lane & 15;
    const int wm   = wid >> 1, wn = wid & 1;
    const int srow = lane >> 2;        // 0..15
    const int sk   = (lane & 3) * 8;   // k element offset 0/8/16/24

    if (blockIdx.x < 512) {
        // ----- gemm1 path: bn fastest (4 blocks share an A-tile) -----
        const int bm = (blockIdx.x >> 2) * 64;
        const int bn = (blockIdx.x & 3) * 64;

        f32x4 acc[2][2];
#pragma unroll
        for (int a = 0; a < 2; ++a)
#pragma unroll
            for (int b = 0; b < 2; ++b) acc[a][b] = (f32x4){0.f, 0.f, 0.f, 0.f};

        const unsigned short* Ag = hvb  + (size_t)(bm + wid * 16 + srow) * KHV + sk;
        const unsigned short* Bg = Winb + (size_t)(bn + wid * 16 + srow) * KHV + sk;
        unsigned short* lA = &sA[(wid * 16) * 32];
        unsigned short* lB = &sB[(wid * 16) * 32];

        for (int kt = 0; kt < KHV; kt += 32) {
            g2l16(Ag + kt, lA);
            g2l16(Bg + kt, lB);
            __syncthreads();
            bf16x8 aF[2], bF[2];
#pragma unroll
            for (int t = 0; t < 2; ++t)
                aF[t] = *(const bf16x8*)&sA[(wm * 32 + t * 16 + l15) * 32 + quad * 8];
#pragma unroll
            for (int t = 0; t < 2; ++t)
                bF[t] = *(const bf16x8*)&sB[(wn * 32 + t * 16 + l15) * 32 + quad * 8];
#pragma unroll
            for (int tm = 0; tm < 2; ++tm)
#pragma unroll
                for (int tn = 0; tn < 2; ++tn)
                    acc[tm][tn] = __builtin_amdgcn_mfma_f32_16x16x32_bf16(
                        aF[tm], bF[tn], acc[tm][tn], 0, 0, 0);
            __syncthreads();
        }

#pragma unroll
        for (int tm = 0; tm < 2; ++tm)
#pragma unroll
            for (int tn = 0; tn < 2; ++tn) {
                const int n = bn + wn * 32 + tn * 16 + l15;
                const float bias = b_in[n];
#pragma unroll
                for (int r = 0; r < 4; ++r) {
                    const int m = bm + wm * 32 + tm * 16 + quad * 4 + r;
                    float x = acc[tm][tn][r] + bias;
                    float s = x * fsigmoid(x);
                    ctrl[(size_t)m * CDIM + n] = f2bf(s);
                }
            }
    } else {
        // ----- gemm3 path: m fastest (64 m-tiles x 16 n-tiles) -----
        const int t3 = blockIdx.x - 512;
        const int bm = (t3 & 63) * 128;
        const int bn = (t3 >> 6) * 128;

        f32x4 acc[4][4];
#pragma unroll
        for (int a = 0; a < 4; ++a)
#pragma unroll
            for (int b = 0; b < 4; ++b) acc[a][b] = (f32x4){0.f, 0.f, 0.f, 0.f};

        const unsigned short* Ag0 = hvb  + (size_t)(bm + wid * 16 + srow) * KHV + sk;
        const unsigned short* Ag1 = hvb  + (size_t)(bm + (wid + 4) * 16 + srow) * KHV + sk;
        const unsigned short* Bg0 = Wmub + (size_t)(bn + wid * 16 + srow) * HDIM + sk;
        const unsigned short* Bg1 = Wmub + (size_t)(bn + (wid + 4) * 16 + srow) * HDIM + sk;
        unsigned short* lA0 = &sA[(wid * 16) * 32];
        unsigned short* lA1 = &sA[((wid + 4) * 16) * 32];
        unsigned short* lB0 = &sB[(wid * 16) * 32];
        unsigned short* lB1 = &sB[((wid + 4) * 16) * 32];

        for (int kt = 0; kt < HDIM; kt += 32) {
            g2l16(Ag0 + kt, lA0);
            g2l16(Ag1 + kt, lA1);
            g2l16(Bg0 + kt, lB0);
            g2l16(Bg1 + kt, lB1);
            __syncthreads();
            bf16x8 aF[4], bF[4];
#pragma unroll
            for (int t = 0; t < 4; ++t)
                aF[t] = *(const bf16x8*)&sA[(wm * 64 + t * 16 + l15) * 32 + quad * 8];
#pragma unroll
            for (int t = 0; t < 4; ++t)
                bF[t] = *(const bf16x8*)&sB[(wn * 64 + t * 16 + l15) * 32 + quad * 8];
#pragma unroll
            for (int tm = 0; tm < 4; ++tm)
#pragma unroll
                for (int tn = 0; tn < 4; ++tn)
                    acc[tm][tn] = __builtin_amdgcn_mfma_f32_16x16x32_bf16(
                        aF[tm], bF[tn], acc[tm][tn], 0, 0, 0);
            __syncthreads();
        }

#pragma unroll
        for (int tm = 0; tm < 4; ++tm)
#pragma unroll
            for (int tn = 0; tn < 4; ++tn) {
                const int n = bn + wn * 64 + tn * 16 + l15;
                const float mub = mu[n];
#pragma unroll
                for (int r = 0; r < 4; ++r) {
                    const int m = bm + wm * 64 + tm * 16 + quad * 4 + r;
                    outmu[(size_t)m * HDIM + n] = acc[tm][tn][r] + mub;
                }
            }
    }
}

// ---------------- K3: ctrl_out (3 planes) + full fused elementwise -------
// A = ctrl [8192 x 256] bf16, Bw = Wout_b [6144 x 256]
// BM=64, BN=64 per plane x 3 planes; 4 waves (2x2), wave tile 32x32/plane
// Epilogue uses native v_exp/v_log/v_rcp and bf16 h/v (from hv_b).
__global__ __launch_bounds__(256, 4)
void k_gemm2(const unsigned short* __restrict__ A,
             const unsigned short* __restrict__ Bw,
             const float* __restrict__ b_out,
             const unsigned short* __restrict__ hv,   // bf16 [B, 4096]: h | v
             const float* __restrict__ mu_ctx,
             float* __restrict__ outp)
{
    __shared__ unsigned short sA[64 * 32];
    __shared__ unsigned short sB[3][64 * 32];
    const int tid  = threadIdx.x;
    const int wid  = tid >> 6;
    const int lane = tid & 63;
    const int quad = lane >> 4;
    const int l15  = lane & 15;
    const int wm   = wid >> 1, wn = wid & 1;
    const int bm   = blockIdx.x * 64;
    const int bn   = blockIdx.y * 64;
    const int srow = lane >> 2;
    const int sk   = (lane & 3) * 8;

    f32x4 acc[3][2][2];
#pragma unroll
    for (int p = 0; p < 3; ++p)
#pragma unroll
        for (int a = 0; a < 2; ++a)
#pragma unroll
            for (int b = 0; b < 2; ++b) acc[p][a][b] = (f32x4){0.f, 0.f, 0.f, 0.f};

    const unsigned short* Ag  = A + (size_t)(bm + wid * 16 + srow) * CDIM + sk;
    const unsigned short* Bg0 = Bw + (size_t)(0 * HDIM + bn + wid * 16 + srow) * CDIM + sk;
    const unsigned short* Bg1 = Bw + (size_t)(1 * HDIM + bn + wid * 16 + srow) * CDIM + sk;
    const unsigned short* Bg2 = Bw + (size_t)(2 * HDIM + bn + wid * 16 + srow) * CDIM + sk;
    unsigned short* lA  = &sA[(wid * 16) * 32];
    unsigned short* lB0 = &sB[0][(wid * 16) * 32];
    unsigned short* lB1 = &sB[1][(wid * 16) * 32];
    unsigned short* lB2 = &sB[2][(wid * 16) * 32];

    for (int kt = 0; kt < CDIM; kt += 32) {
        g2l16(Ag  + kt, lA);
        g2l16(Bg0 + kt, lB0);
        g2l16(Bg1 + kt, lB1);
        g2l16(Bg2 + kt, lB2);
        __syncthreads();
        bf16x8 aF[2], bF[3][2];
#pragma unroll
        for (int t = 0; t < 2; ++t)
            aF[t] = *(const bf16x8*)&sA[(wm * 32 + t * 16 + l15) * 32 + quad * 8];
#pragma unroll
        for (int p = 0; p < 3; ++p)
#pragma unroll
            for (int t = 0; t < 2; ++t)
                bF[p][t] = *(const bf16x8*)&sB[p][(wn * 32 + t * 16 + l15) * 32 + quad * 8];
#pragma unroll
        for (int p = 0; p < 3; ++p)
#pragma unroll
            for (int tm = 0; tm < 2; ++tm)
#pragma unroll
                for (int tn = 0; tn < 2; ++tn)
                    acc[p][tm][tn] = __builtin_amdgcn_mfma_f32_16x16x32_bf16(
                        aF[tm], bF[p][tn], acc[p][tm][tn], 0, 0, 0);
        __syncthreads();
    }

#pragma unroll
    for (int tm = 0; tm < 2; ++tm)
#pragma unroll
        for (int tn = 0; tn < 2; ++tn) {
            const int i  = bn + wn * 32 + tn * 16 + l15;
            const float ba = b_out[i];
            const float bb = b_out[HDIM + i];
            const float bg = b_out[2 * HDIM + i];
#pragma unroll
            for (int r = 0; r < 4; ++r) {
                const int m = bm + wm * 32 + tm * 16 + quad * 4 + r;
                const size_t off = (size_t)m * HDIM + i;
                const float araw = acc[0][tm][tn][r] + ba;
                const float braw = acc[1][tm][tn][r] + bb;
                const float graw = acc[2][tm][tn][r] + bg;
                const float alpha = fsigmoid(araw);
                const float beta  = fminf(fsoftplus(braw), 2.f);
                const float gate  = fsigmoid(graw);
                const float hh = bf2f(hv[(size_t)m * KHV + i]);
                const float vv = bf2f(hv[(size_t)m * KHV + HDIM + i]);
                const float mm = mu_ctx[off];
                const float err = hh - mm;
                float vn = alpha * vv - beta * err;
                vn = fminf(fmaxf(vn, -10.f), 10.f);
                const float hn = hh + DT_C * gate * vn;
                outp[off] = hn;                              // h_next
                outp[(size_t)B_TOK * HDIM + off] = vn;       // v_next
            }
        }
}

extern "C" void kernel_launch(void* const* d_in, const int* in_sizes, int n_in,
                              void* d_out, int out_size, void* d_ws, size_t ws_size,
                              hipStream_t stream)
{
    const float* hp    = (const float*)d_in[0];
    const float* vp    = (const float*)d_in[1];
    const float* Win   = (const float*)d_in[2];
    const float* b_in  = (const float*)d_in[3];
    const float* Wout  = (const float*)d_in[4];
    const float* b_out = (const float*)d_in[5];
    const float* Wmu   = (const float*)d_in[6];
    const float* mu    = (const float*)d_in[7];
    float* outp = (float*)d_out;

    char* ws = (char*)d_ws;
    size_t off = 0;
    unsigned short* hv_b   = (unsigned short*)(ws + off); off += (size_t)B_TOK * KHV * 2;  // 64 MiB
    unsigned short* Wmu_b  = (unsigned short*)(ws + off); off += (size_t)HDIM * HDIM * 2;  //  8 MiB
    unsigned short* Wout_b = (unsigned short*)(ws + off); off += (size_t)N3H * CDIM * 2;   //  3 MiB
    unsigned short* Win_b  = (unsigned short*)(ws + off); off += (size_t)CDIM * KHV * 2;   //  2 MiB
    unsigned short* ctrl   = (unsigned short*)(ws + off); off += (size_t)B_TOK * CDIM * 2; //  4 MiB
    // total ws use ~81 MiB

    k_convert<<<dim3(4096), dim3(256), 0, stream>>>(
        hp, vp, Win, Wout, Wmu,
        (ushort4*)hv_b, (ushort4*)Wmu_b, (ushort4*)Wout_b, (ushort4*)Win_b);

    // fat kernel: gemm1 (512 blocks) + gemm3 (1024 blocks), independent work
    k_mid<<<dim3(1536), dim3(256), 0, stream>>>(
        hv_b, Win_b, Wmu_b, b_in, mu, ctrl, outp + (size_t)2 * B_TOK * HDIM);

    k_gemm2<<<dim3(128, 32), dim3(256), 0, stream>>>(
        ctrl, Wout_b, b_out, hv_b,
        outp + (size_t)2 * B_TOK * HDIM, outp);
}